// Round 1
// baseline (527.165 us; speedup 1.0000x reference)
//
#include <hip/hip_runtime.h>

#define BLOCK 256

// Mahalanobis AR(1) loss:
//   quad[b] = sum_i d_i^2 + 2*coef * sum_i d_i*d_{i+1},  d = (y_true-y_pred)*mask(t<n[b])
//   out = mean_b quad[b]/n[b]
// D = 64 floats = 16 float4 per row; lane l handles float4 col4 = g&15.
__global__ __launch_bounds__(BLOCK) void mahal_kernel(
    const float* __restrict__ y_true,
    const float* __restrict__ y_pred,
    const float* __restrict__ param,
    const int*   __restrict__ n,
    float* __restrict__ out,
    int total_vec4,   // B*D/4
    float invB)
{
    // coef = -p/(1+p^2), p = 2*sigmoid(param)-1
    float t = param[0];
    float p = 2.0f / (1.0f + __expf(-t)) - 1.0f;
    float coef2 = -2.0f * p / (1.0f + p * p);   // 2*coef

    const float4* yt4 = (const float4*)y_true;
    const float4* yp4 = (const float4*)y_pred;

    float acc = 0.0f;
    int stride = gridDim.x * BLOCK;
    for (int g = blockIdx.x * BLOCK + threadIdx.x; g < total_vec4; g += stride) {
        int row  = g >> 4;       // D/4 = 16 float4 per row
        int col4 = g & 15;
        int e0   = col4 << 2;    // first element index in row
        int nv   = n[row];
        float4 a = yt4[g];
        float4 b = yp4[g];
        float d0 = (e0 + 0 < nv) ? (a.x - b.x) : 0.0f;
        float d1 = (e0 + 1 < nv) ? (a.y - b.y) : 0.0f;
        float d2 = (e0 + 2 < nv) ? (a.z - b.z) : 0.0f;
        float d3 = (e0 + 3 < nv) ? (a.w - b.w) : 0.0f;
        float sumsq = d0 * d0 + d1 * d1 + d2 * d2 + d3 * d3;
        float cross = d0 * d1 + d1 * d2 + d2 * d3;
        // boundary pair (4k+3, 4k+4): neighbor lane's d0. Lane col4==15 is the
        // row end (its own d3 pairs with nothing); grid base is a multiple of
        // 16 so col4 == (lane & 15) and the shuffle never crosses a row
        // within the lanes that use it.
        float nb = __shfl_down(d0, 1, 64);
        if (col4 != 15) cross += d3 * nb;
        acc += (sumsq + coef2 * cross) / (float)nv;
    }

    // wave reduction (64 lanes)
    #pragma unroll
    for (int off = 32; off >= 1; off >>= 1)
        acc += __shfl_down(acc, off, 64);

    __shared__ float smem[BLOCK / 64];
    int lane = threadIdx.x & 63;
    int wid  = threadIdx.x >> 6;
    if (lane == 0) smem[wid] = acc;
    __syncthreads();
    if (threadIdx.x == 0) {
        float s = 0.0f;
        #pragma unroll
        for (int i = 0; i < BLOCK / 64; ++i) s += smem[i];
        atomicAdd(out, s * invB);
    }
}

extern "C" void kernel_launch(void* const* d_in, const int* in_sizes, int n_in,
                              void* d_out, int out_size, void* d_ws, size_t ws_size,
                              hipStream_t stream) {
    const float* y_true = (const float*)d_in[0];
    const float* y_pred = (const float*)d_in[1];
    const float* param  = (const float*)d_in[2];
    const int*   n      = (const int*)d_in[3];
    float* out = (float*)d_out;

    int total = in_sizes[0];        // B*D
    int B     = in_sizes[3];        // rows
    int total_vec4 = total / 4;
    float invB = 1.0f / (float)B;

    // d_out is poisoned 0xAA before every timed launch — zero it in-stream.
    hipMemsetAsync(out, 0, sizeof(float) * out_size, stream);

    int blocks = 8192;              // grid-stride: 8 float4 iters/thread at B=1M,D=64
    int max_blocks = (total_vec4 + BLOCK - 1) / BLOCK;
    if (blocks > max_blocks) blocks = max_blocks;
    mahal_kernel<<<blocks, BLOCK, 0, stream>>>(y_true, y_pred, param, n, out,
                                               total_vec4, invB);
}

// Round 2
// 520.188 us; speedup vs baseline: 1.0134x; 1.0134x over previous
//
#include <hip/hip_runtime.h>

#define BLOCK 256
#define UNROLL 8

// Mahalanobis AR(1) loss, latency-optimized:
//   quad[b] = sum d_i^2 + 2*coef*sum d_i*d_{i+1},  d = (y_true-y_pred)*mask(t<n[b])
//   out = mean_b quad[b]/n[b]
// Each block owns a contiguous chunk of BLOCK*UNROLL float4; every thread
// issues all 8x2 float4 loads + 8 n-loads up front (16 outstanding vmem ops)
// before any arithmetic, to cover ~900-cycle HBM latency.
__global__ __launch_bounds__(BLOCK) void mahal_kernel(
    const float4* __restrict__ yt4,
    const float4* __restrict__ yp4,
    const float*  __restrict__ param,
    const int*    __restrict__ n,
    float* __restrict__ out,
    int total_vec4,   // B*D/4
    float invB)
{
    float t = param[0];
    float p = 2.0f / (1.0f + __expf(-t)) - 1.0f;
    float coef2 = -2.0f * p / (1.0f + p * p);   // 2*coef

    const int chunk = BLOCK * UNROLL;
    int base = blockIdx.x * chunk + (int)threadIdx.x;

    float4 a[UNROLL], b[UNROLL];
    int veff[UNROLL];

    // ---- issue ALL loads first (independent, coalesced: lane i -> 16B at base+i) ----
    #pragma unroll
    for (int j = 0; j < UNROLL; ++j) {
        int gj = base + j * BLOCK;
        int g  = gj < total_vec4 ? gj : total_vec4 - 1;  // clamp: load always valid
        a[j] = yt4[g];
        b[j] = yp4[g];
        veff[j] = (gj < total_vec4) ? n[g >> 4] : 0;     // 0 => contribution zeroed
    }

    // chunk and BLOCK are multiples of 16, so col4 is the same for every j
    int col4 = threadIdx.x & 15;
    int e0   = col4 << 2;
    bool not_last = (col4 != 15);
    float acc = 0.0f;

    #pragma unroll
    for (int j = 0; j < UNROLL; ++j) {
        int v = veff[j];
        float d0 = (e0 + 0 < v) ? (a[j].x - b[j].x) : 0.0f;
        float d1 = (e0 + 1 < v) ? (a[j].y - b[j].y) : 0.0f;
        float d2 = (e0 + 2 < v) ? (a[j].z - b[j].z) : 0.0f;
        float d3 = (e0 + 3 < v) ? (a[j].w - b[j].w) : 0.0f;
        // boundary pair (e0+3, e0+4): neighbor lane's d0 (unconditional shuffle,
        // all lanes execute; v==0 lanes contribute d0=0)
        float nb = __shfl_down(d0, 1, 64);
        float sumsq = d0 * d0 + d1 * d1 + d2 * d2 + d3 * d3;
        float cross = d0 * d1 + d1 * d2 + d2 * d3;
        if (not_last) cross += d3 * nb;
        float q = fmaf(coef2, cross, sumsq);
        // v==0 => sumsq==cross==0 => q==0, rcp value irrelevant
        acc = fmaf(q, __builtin_amdgcn_rcpf((float)v), acc);
    }

    // wave reduction (64 lanes)
    #pragma unroll
    for (int off = 32; off >= 1; off >>= 1)
        acc += __shfl_down(acc, off, 64);

    __shared__ float smem[BLOCK / 64];
    int lane = threadIdx.x & 63;
    int wid  = threadIdx.x >> 6;
    if (lane == 0) smem[wid] = acc;
    __syncthreads();
    if (threadIdx.x == 0) {
        float s = 0.0f;
        #pragma unroll
        for (int i = 0; i < BLOCK / 64; ++i) s += smem[i];
        atomicAdd(out, s * invB);
    }
}

extern "C" void kernel_launch(void* const* d_in, const int* in_sizes, int n_in,
                              void* d_out, int out_size, void* d_ws, size_t ws_size,
                              hipStream_t stream) {
    const float* y_true = (const float*)d_in[0];
    const float* y_pred = (const float*)d_in[1];
    const float* param  = (const float*)d_in[2];
    const int*   n      = (const int*)d_in[3];
    float* out = (float*)d_out;

    int total = in_sizes[0];        // B*D
    int B     = in_sizes[3];        // rows
    int total_vec4 = total / 4;
    float invB = 1.0f / (float)B;

    // d_out is poisoned 0xAA before every timed launch — zero it in-stream.
    hipMemsetAsync(out, 0, sizeof(float) * out_size, stream);

    const int chunk = BLOCK * UNROLL;
    int blocks = (total_vec4 + chunk - 1) / chunk;   // 8192 at B=1M, D=64
    mahal_kernel<<<blocks, BLOCK, 0, stream>>>((const float4*)y_true,
                                               (const float4*)y_pred,
                                               param, n, out,
                                               total_vec4, invB);
}

// Round 3
// 505.089 us; speedup vs baseline: 1.0437x; 1.0299x over previous
//
#include <hip/hip_runtime.h>

#define BLOCK 256
#define UNROLL 8
#define CHUNK (BLOCK * UNROLL)   // float4 elements per block

// Mahalanobis AR(1) loss:
//   quad[b] = sum d_i^2 + 2*coef*sum d_i*d_{i+1},  d = (y_true-y_pred)*mask(t<n[b])
//   out = mean_b quad[b]/n[b]
// D = 64 floats = 16 float4/row; lane handles col4 = tid&15.
//
// R3: sched_barrier(0) pins all 17 vmem ops per thread BEFORE any compute
// (R2's two-loop structure was re-fused by the scheduler: VGPR=40 proved the
// prefetch was sunk). Partial sums go to d_ws; no global atomics.
__global__ __launch_bounds__(BLOCK) void mahal_main(
    const float4* __restrict__ yt4,
    const float4* __restrict__ yp4,
    const float*  __restrict__ param,
    const int*    __restrict__ n,
    float* __restrict__ partial,
    int total_vec4)
{
    float t = param[0];
    float p = 2.0f / (1.0f + __expf(-t)) - 1.0f;
    float coef2 = -2.0f * p / (1.0f + p * p);   // 2*coef

    int base = blockIdx.x * CHUNK + (int)threadIdx.x;

    float4 a[UNROLL], b[UNROLL];
    int    vv[UNROLL];

    if ((blockIdx.x + 1) * CHUNK <= total_vec4) {
        // fast path (block-uniform): all loads in range, no clamping
        #pragma unroll
        for (int j = 0; j < UNROLL; ++j) {
            int g = base + j * BLOCK;
            a[j]  = yt4[g];
            b[j]  = yp4[g];
            vv[j] = n[g >> 4];
        }
    } else {
        #pragma unroll
        for (int j = 0; j < UNROLL; ++j) {
            int gj = base + j * BLOCK;
            int g  = gj < total_vec4 ? gj : 0;
            a[j]  = yt4[g];
            b[j]  = yp4[g];
            vv[j] = (gj < total_vec4) ? n[g >> 4] : 0;   // 0 => masked out below
        }
    }
    // Forbid the scheduler from sinking loads into the compute loop:
    __builtin_amdgcn_sched_barrier(0);

    int col4 = threadIdx.x & 15;
    int e0   = col4 << 2;
    bool not_last = (col4 != 15);
    float acc = 0.0f;

    #pragma unroll
    for (int j = 0; j < UNROLL; ++j) {
        int v = vv[j];
        float d0 = (e0 + 0 < v) ? (a[j].x - b[j].x) : 0.0f;
        float d1 = (e0 + 1 < v) ? (a[j].y - b[j].y) : 0.0f;
        float d2 = (e0 + 2 < v) ? (a[j].z - b[j].z) : 0.0f;
        float d3 = (e0 + 3 < v) ? (a[j].w - b[j].w) : 0.0f;
        // boundary pair (e0+3, e0+4): neighbor lane's d0; lane col4==15 is row end
        float nb = __shfl_down(d0, 1, 64);
        float sumsq = d0 * d0 + d1 * d1 + d2 * d2 + d3 * d3;
        float cross = d0 * d1 + d1 * d2 + d2 * d3;
        if (not_last) cross += d3 * nb;
        float q  = fmaf(coef2, cross, sumsq);
        // v==0 (tail) => q==0; avoid 0*rcp(0)=NaN by clamping divisor to 1
        float rv = __builtin_amdgcn_rcpf((float)(v > 0 ? v : 1));
        acc = fmaf(q, rv, acc);
    }

    // wave reduction (64 lanes)
    #pragma unroll
    for (int off = 32; off >= 1; off >>= 1)
        acc += __shfl_down(acc, off, 64);

    __shared__ float smem[BLOCK / 64];
    int lane = threadIdx.x & 63;
    int wid  = threadIdx.x >> 6;
    if (lane == 0) smem[wid] = acc;
    __syncthreads();
    if (threadIdx.x == 0) {
        float s = 0.0f;
        #pragma unroll
        for (int i = 0; i < BLOCK / 64; ++i) s += smem[i];
        partial[blockIdx.x] = s;
    }
}

// Single-block reduction of per-block partials; writes the final mean.
__global__ __launch_bounds__(256) void mahal_finish(
    const float* __restrict__ partial,
    float* __restrict__ out,
    int nblocks, float invB)
{
    float acc = 0.0f;
    if ((nblocks & 3) == 0) {
        const float4* p4 = (const float4*)partial;
        int n4 = nblocks >> 2;
        for (int i = threadIdx.x; i < n4; i += 256) {
            float4 v = p4[i];
            acc += v.x + v.y + v.z + v.w;
        }
    } else {
        for (int i = threadIdx.x; i < nblocks; i += 256)
            acc += partial[i];
    }
    #pragma unroll
    for (int off = 32; off >= 1; off >>= 1)
        acc += __shfl_down(acc, off, 64);
    __shared__ float smem[4];
    int lane = threadIdx.x & 63;
    int wid  = threadIdx.x >> 6;
    if (lane == 0) smem[wid] = acc;
    __syncthreads();
    if (threadIdx.x == 0)
        out[0] = (smem[0] + smem[1] + smem[2] + smem[3]) * invB;
}

extern "C" void kernel_launch(void* const* d_in, const int* in_sizes, int n_in,
                              void* d_out, int out_size, void* d_ws, size_t ws_size,
                              hipStream_t stream) {
    const float* y_true = (const float*)d_in[0];
    const float* y_pred = (const float*)d_in[1];
    const float* param  = (const float*)d_in[2];
    const int*   n      = (const int*)d_in[3];
    float* out = (float*)d_out;

    int total = in_sizes[0];        // B*D
    int B     = in_sizes[3];        // rows
    int total_vec4 = total / 4;
    float invB = 1.0f / (float)B;

    int blocks = (total_vec4 + CHUNK - 1) / CHUNK;   // 8192 at B=1M, D=64
    float* partial = (float*)d_ws;                   // needs blocks*4 bytes

    mahal_main<<<blocks, BLOCK, 0, stream>>>((const float4*)y_true,
                                             (const float4*)y_pred,
                                             param, n, partial, total_vec4);
    mahal_finish<<<1, 256, 0, stream>>>(partial, out, blocks, invB);
}